// Round 5
// baseline (687.254 us; speedup 1.0000x reference)
//
#include <hip/hip_runtime.h>
#include <cfloat>

#define NTOK 65536
#define DIM  512
#define KCB  1024
#define TAU  0.05f
#define REF_CAP 4096

typedef unsigned short u16;
typedef __attribute__((ext_vector_type(8))) short short8;
typedef __attribute__((ext_vector_type(4))) float f32x4;

// ---------------- ws layout (bytes) ----------------
// 0       : idx       int[NTOK]        262144
// 262144  : esq       f32[KCB]         4096    -> 266240
// 266240  : refCount  int (16B pad)            -> 266256
// 266256  : refList   int[REF_CAP]     16384   -> 282640
// 282640  : n         f32                      -> 282656 (pad)
// 282656  : counts    int[KCB]         4096    -> 286752
// 286752  : cursor    int[KCB]         4096    -> 290848
// 290848  : base      int[KCB]         4096    -> 294944
// 294976  : E_hi      u16[KCB*DIM]     1048576 -> 1343552
// 1343552 : E_lo      u16[KCB*DIM]     1048576 -> 2392128
// toklist int[NTOK] aliases E_lo (dead after score_kernel)

__device__ __forceinline__ u16 f2bf(float f) {
    unsigned int u = __float_as_uint(f);
    u += 0x7FFF + ((u >> 16) & 1);
    return (u16)(u >> 16);
}
__device__ __forceinline__ float bf2f(u16 h) {
    return __uint_as_float(((unsigned int)h) << 16);
}

__global__ __launch_bounds__(256) void esq_kernel(const float* __restrict__ E,
                                                  float* __restrict__ esq)
{
    const int lane = threadIdx.x & 63;
    const int wv   = threadIdx.x >> 6;
    const int k    = blockIdx.x * 4 + wv;
    const float* er = E + (size_t)k * DIM + lane * 8;
    float4 a = *(const float4*)er;
    float4 b = *(const float4*)(er + 4);
    float s = a.x*a.x + a.y*a.y + a.z*a.z + a.w*a.w
            + b.x*b.x + b.y*b.y + b.z*b.z + b.w*b.w;
    for (int off = 32; off > 0; off >>= 1) s += __shfl_down(s, off, 64);
    if (lane == 0) esq[k] = s;
}

// Decompose E into bf16 hi + bf16 residual lo (row-major [KCB][DIM])
__global__ __launch_bounds__(256) void ehilo_kernel(const float* __restrict__ E,
                                                    u16* __restrict__ Ehi,
                                                    u16* __restrict__ Elo)
{
    const size_t i = (size_t)blockIdx.x * 256 + threadIdx.x;   // pair index
    const float2 v = *(const float2*)(E + i * 2);
    const u16 h0 = f2bf(v.x), h1 = f2bf(v.y);
    const u16 l0 = f2bf(v.x - bf2f(h0)), l1 = f2bf(v.y - bf2f(h1));
    ((unsigned int*)Ehi)[i] = ((unsigned int)h1 << 16) | h0;
    ((unsigned int*)Elo)[i] = ((unsigned int)l1 << 16) | l0;
}

// MFMA split-bf16 scoring: 64 tokens/block (16/wave, K=512 in regs),
// 64 chunks of 16 codes staged in swizzled LDS.
__global__ __launch_bounds__(256, 2) void score_kernel(
    const float* __restrict__ z,
    const u16* __restrict__ Ehi, const u16* __restrict__ Elo,
    const float* __restrict__ esq,
    int* __restrict__ idx_ws, float* __restrict__ idx_out,
    int* __restrict__ refCount, int* __restrict__ refList)
{
    __shared__ u16 ehi_t[16 * 512];     // 16 KB, slot-swizzled rows
    __shared__ u16 elo_t[16 * 512];     // 16 KB
    __shared__ float esq_lds[KCB];      // 4 KB

    const int tid  = threadIdx.x;
    const int lane = tid & 63;
    const int wv   = tid >> 6;
    const int blk  = blockIdx.x;
    const int tokbase = blk * 64 + wv * 16;

    for (int i = tid; i < KCB; i += 256) esq_lds[i] = esq[i];

    // A fragments: 16 tokens x K=512, bf16 hi/lo, in registers
    short8 zh[16], zl[16];
    {
        const float* zr = z + (size_t)(tokbase + (lane & 15)) * DIM + ((lane >> 4) << 3);
        #pragma unroll
        for (int kc = 0; kc < 16; ++kc) {
            float4 a = *(const float4*)(zr + kc * 32);
            float4 b = *(const float4*)(zr + kc * 32 + 4);
            float v[8] = {a.x, a.y, a.z, a.w, b.x, b.y, b.z, b.w};
            short8 h, l;
            #pragma unroll
            for (int j = 0; j < 8; ++j) {
                const u16 hb = f2bf(v[j]);
                h[j] = (short)hb;
                l[j] = (short)f2bf(v[j] - bf2f(hb));
            }
            zh[kc] = h; zl[kc] = l;
        }
    }

    float d1[4], d2[4]; int i1[4];
    #pragma unroll
    for (int r = 0; r < 4; ++r) { d1[r] = FLT_MAX; d2[r] = FLT_MAX; i1[r] = KCB; }

    for (int ch = 0; ch < 64; ++ch) {
        __syncthreads();
        #pragma unroll
        for (int i = 0; i < 4; ++i) {
            const int c = (wv << 2) + i;
            const size_t grow = (size_t)((ch << 4) + c) * 512;
            const int soff = (lane ^ (c & 7)) << 3;
            __builtin_amdgcn_global_load_lds(
                (const __attribute__((address_space(1))) void*)(Ehi + grow + soff),
                (__attribute__((address_space(3))) void*)&ehi_t[c * 512], 16, 0, 0);
            __builtin_amdgcn_global_load_lds(
                (const __attribute__((address_space(1))) void*)(Elo + grow + soff),
                (__attribute__((address_space(3))) void*)&elo_t[c * 512], 16, 0, 0);
        }
        __syncthreads();

        f32x4 acc = {0.f, 0.f, 0.f, 0.f};
        #pragma unroll
        for (int kc = 0; kc < 16; ++kc) {
            const int slot = (kc << 2) + (lane >> 4);
            const int base = (lane & 15) * 512 + ((slot ^ (lane & 7)) << 3);
            const short8 eh = *(const short8*)&ehi_t[base];
            const short8 el = *(const short8*)&elo_t[base];
            acc = __builtin_amdgcn_mfma_f32_16x16x32_bf16(zh[kc], eh, acc, 0, 0, 0);
            acc = __builtin_amdgcn_mfma_f32_16x16x32_bf16(zh[kc], el, acc, 0, 0, 0);
            acc = __builtin_amdgcn_mfma_f32_16x16x32_bf16(zl[kc], eh, acc, 0, 0, 0);
        }

        const int code = (ch << 4) + (lane & 15);
        const float ej = esq_lds[code];
        #pragma unroll
        for (int r = 0; r < 4; ++r) {
            const float dist = fmaf(-2.0f, acc[r], ej);
            if (dist < d1[r]) { d2[r] = d1[r]; d1[r] = dist; i1[r] = code; }
            else              { d2[r] = fminf(d2[r], dist); }
        }
    }

    #pragma unroll
    for (int off = 1; off < 16; off <<= 1) {
        #pragma unroll
        for (int r = 0; r < 4; ++r) {
            const float od1 = __shfl_xor(d1[r], off, 64);
            const int   oi1 = __shfl_xor(i1[r], off, 64);
            const float od2 = __shfl_xor(d2[r], off, 64);
            float loser;
            if (od1 < d1[r] || (od1 == d1[r] && oi1 < i1[r])) {
                loser = d1[r]; d1[r] = od1; i1[r] = oi1;
            } else {
                loser = od1;
            }
            d2[r] = fminf(fminf(d2[r], od2), loser);
        }
    }
    if ((lane & 15) == 0) {
        #pragma unroll
        for (int r = 0; r < 4; ++r) {
            const int token = tokbase + ((lane >> 4) << 2) + r;
            idx_ws[token]  = i1[r];
            idx_out[token] = (float)i1[r];
            if (d2[r] - d1[r] < TAU) {
                int slot = atomicAdd(refCount, 1);
                if (slot < REF_CAP) refList[slot] = token;
            }
        }
    }
}

// f64 exact re-scoring of near-tie tokens against all 1024 codes
__global__ __launch_bounds__(256) void refine_kernel(
    const float* __restrict__ z, const float* __restrict__ E,
    const int* __restrict__ refCount, const int* __restrict__ refList,
    int* __restrict__ idx_ws, float* __restrict__ idx_out)
{
    __shared__ double dists[KCB];
    const int lane = threadIdx.x & 63;
    const int wv   = threadIdx.x >> 6;
    int rc = *refCount; if (rc > REF_CAP) rc = REF_CAP;
    for (int r = blockIdx.x; r < rc; r += gridDim.x) {
        const int token = refList[r];
        double zr[8];
        const float* zp = z + (size_t)token * DIM + lane * 8;
        #pragma unroll
        for (int j = 0; j < 8; ++j) zr[j] = (double)zp[j];
        for (int c = wv; c < KCB; c += 4) {
            const float* ep = E + (size_t)c * DIM + lane * 8;
            double s = 0.0;
            #pragma unroll
            for (int j = 0; j < 8; ++j) { const double df = zr[j] - (double)ep[j]; s = fma(df, df, s); }
            for (int off = 32; off > 0; off >>= 1) s += __shfl_down(s, off, 64);
            if (lane == 0) dists[c] = s;
        }
        __syncthreads();
        if (threadIdx.x < 64) {
            double best = dists[lane]; int bi = lane;
            for (int c = lane + 64; c < KCB; c += 64) {
                const double dv = dists[c];
                if (dv < best) { best = dv; bi = c; }
            }
            for (int off = 32; off > 0; off >>= 1) {
                const double ob = __shfl_down(best, off, 64);
                const int    oi = __shfl_down(bi, off, 64);
                if (ob < best || (ob == best && oi < bi)) { best = ob; bi = oi; }
            }
            if (lane == 0) { idx_ws[token] = bi; idx_out[token] = (float)bi; }
        }
        __syncthreads();
    }
}

// ---- counting sort of tokens by code ----
__global__ __launch_bounds__(256) void hist_kernel(const int* __restrict__ idx,
                                                   int* __restrict__ counts)
{
    __shared__ int h[KCB];
    const int tid = threadIdx.x;
    for (int i = tid; i < KCB; i += 256) h[i] = 0;
    __syncthreads();
    const int b0 = blockIdx.x * 1024;
    #pragma unroll
    for (int j = 0; j < 4; ++j) atomicAdd(&h[idx[b0 + j * 256 + tid]], 1);
    __syncthreads();
    for (int i = tid; i < KCB; i += 256) {
        const int v = h[i];
        if (v) atomicAdd(&counts[i], v);
    }
}

__global__ __launch_bounds__(1024) void scan_kernel(const int* __restrict__ counts,
                                                    int* __restrict__ cursor,
                                                    int* __restrict__ base)
{
    const int tid = threadIdx.x, lane = tid & 63, wv = tid >> 6;
    const int v = counts[tid];
    int s = v;
    #pragma unroll
    for (int off = 1; off < 64; off <<= 1) {
        const int nb = __shfl_up(s, off, 64);
        if (lane >= off) s += nb;
    }
    __shared__ int wsum[16], wbase[16];
    if (lane == 63) wsum[wv] = s;
    __syncthreads();
    if (tid == 0) {
        int r = 0;
        for (int w = 0; w < 16; ++w) { wbase[w] = r; r += wsum[w]; }
    }
    __syncthreads();
    const int excl = wbase[wv] + s - v;
    cursor[tid] = excl;
    base[tid]   = excl;
}

__global__ __launch_bounds__(256) void scatter_kernel(const int* __restrict__ idx,
                                                      int* __restrict__ cursor,
                                                      int* __restrict__ toklist)
{
    const int b0 = blockIdx.x * 1024;
    #pragma unroll
    for (int j = 0; j < 4; ++j) {
        const int t = b0 + j * 256 + threadIdx.x;
        const int k = idx[t];
        const int slot = atomicAdd(&cursor[k], 1);
        toklist[slot] = t;
    }
}

// Block per code: contiguous token list -> z-row sum (4-deep MLP) + fused
// out0 broadcast-write (out0[t] = E[k]) + EMA epilogue for out3/out4.
__global__ __launch_bounds__(256) void sum_kernel(
    const float* __restrict__ z, const float* __restrict__ E,
    const int* __restrict__ toklist, const int* __restrict__ base,
    const int* __restrict__ counts, const float* __restrict__ cs,
    const float* __restrict__ ea,
    float* __restrict__ out0, float* __restrict__ out3, float* __restrict__ out4)
{
    const int k = blockIdx.x, tid = threadIdx.x;
    const int b0 = base[k], cnt = counts[k];
    const int d = tid * 2;
    const float2 er = *(const float2*)(E + (size_t)k * DIM + d);
    float sx = 0.f, sy = 0.f;
    int i = 0;
    for (; i + 4 <= cnt; i += 4) {
        const int t0 = toklist[b0 + i],     t1 = toklist[b0 + i + 1];
        const int t2 = toklist[b0 + i + 2], t3 = toklist[b0 + i + 3];
        const float2 v0 = *(const float2*)(z + (size_t)t0 * DIM + d);
        const float2 v1 = *(const float2*)(z + (size_t)t1 * DIM + d);
        const float2 v2 = *(const float2*)(z + (size_t)t2 * DIM + d);
        const float2 v3 = *(const float2*)(z + (size_t)t3 * DIM + d);
        *(float2*)(out0 + (size_t)t0 * DIM + d) = er;
        *(float2*)(out0 + (size_t)t1 * DIM + d) = er;
        *(float2*)(out0 + (size_t)t2 * DIM + d) = er;
        *(float2*)(out0 + (size_t)t3 * DIM + d) = er;
        sx += v0.x; sy += v0.y; sx += v1.x; sy += v1.y;
        sx += v2.x; sy += v2.y; sx += v3.x; sy += v3.y;
    }
    for (; i < cnt; ++i) {
        const int t = toklist[b0 + i];
        const float2 v = *(const float2*)(z + (size_t)t * DIM + d);
        *(float2*)(out0 + (size_t)t * DIM + d) = er;
        sx += v.x; sy += v.y;
    }
    if (tid == 0) out3[k] = 0.99f * cs[k] + 0.01f * (float)cnt;
    const size_t o = (size_t)k * DIM + d;
    const float2 eav = *(const float2*)(ea + o);
    float2 o4;
    o4.x = 0.99f * eav.x + 0.01f * sx;
    o4.y = 0.99f * eav.y + 0.01f * sy;
    *(float2*)(out4 + o) = o4;
}

__global__ __launch_bounds__(1024) void n_kernel(const float* __restrict__ out3,
                                                 float* __restrict__ n_ws)
{
    const int k = threadIdx.x;
    float s = out3[k];
    for (int off = 32; off > 0; off >>= 1) s += __shfl_down(s, off, 64);
    __shared__ float red[16];
    const int lane = k & 63, wv = k >> 6;
    if (lane == 0) red[wv] = s;
    __syncthreads();
    if (k == 0) {
        float t = 0.f;
        for (int i = 0; i < 16; ++i) t += red[i];
        n_ws[0] = t;
    }
}

__global__ __launch_bounds__(256) void out2_kernel(const float* __restrict__ out4,
    const float* __restrict__ out3, const float* __restrict__ n_ws,
    float* __restrict__ out2)
{
    const size_t i = (size_t)blockIdx.x * 256 + threadIdx.x;
    const int k = (int)(i >> 9);
    const float n = n_ws[0];
    const float smoothed = (out3[k] + 1e-5f) / (n + 0.01024f) * n;
    out2[i] = out4[i] / smoothed;
}

extern "C" void kernel_launch(void* const* d_in, const int* in_sizes, int n_in,
                              void* d_out, int out_size, void* d_ws, size_t ws_size,
                              hipStream_t stream)
{
    const float* z  = (const float*)d_in[0];
    const float* E  = (const float*)d_in[1];
    const float* cs = (const float*)d_in[2];
    const float* ea = (const float*)d_in[3];

    float* out0 = (float*)d_out;                       // quantized_st [NTOK*DIM]
    float* out1 = out0 + (size_t)NTOK * DIM;           // indices (as f32) [NTOK]
    float* out2 = out1 + NTOK;                         // new_embedding [KCB*DIM]
    float* out3 = out2 + (size_t)KCB * DIM;            // new_cluster_size [KCB]
    float* out4 = out3 + KCB;                          // new_embed_avg [KCB*DIM]

    char* ws = (char*)d_ws;
    int*   idx_ws  = (int*)ws;
    float* esq     = (float*)(ws + 262144);
    int*   refCnt  = (int*)(ws + 266240);
    int*   refList = (int*)(ws + 266256);
    float* n_ws    = (float*)(ws + 282640);
    int*   counts  = (int*)(ws + 282656);
    int*   cursor  = (int*)(ws + 286752);
    int*   base    = (int*)(ws + 290848);
    u16*   Ehi     = (u16*)(ws + 294976);
    u16*   Elo     = (u16*)(ws + 1343552);
    int*   toklist = (int*)(ws + 1343552);             // aliases Elo (dead after score)

    hipMemsetAsync(refCnt, 0, sizeof(int), stream);
    hipMemsetAsync(counts, 0, KCB * sizeof(int), stream);

    esq_kernel<<<KCB / 4, 256, 0, stream>>>(E, esq);
    ehilo_kernel<<<(KCB * DIM / 2) / 256, 256, 0, stream>>>(E, Ehi, Elo);
    score_kernel<<<NTOK / 64, 256, 0, stream>>>(z, Ehi, Elo, esq, idx_ws, out1, refCnt, refList);
    refine_kernel<<<256, 256, 0, stream>>>(z, E, refCnt, refList, idx_ws, out1);
    hist_kernel<<<NTOK / 1024, 256, 0, stream>>>(idx_ws, counts);
    scan_kernel<<<1, 1024, 0, stream>>>(counts, cursor, base);
    scatter_kernel<<<NTOK / 1024, 256, 0, stream>>>(idx_ws, cursor, toklist);
    sum_kernel<<<KCB, 256, 0, stream>>>(z, E, toklist, base, counts, cs, ea, out0, out3, out4);
    n_kernel<<<1, 1024, 0, stream>>>(out3, n_ws);
    out2_kernel<<<(KCB * DIM) / 256, 256, 0, stream>>>(out4, out3, n_ws, out2);
}

// Round 6
// 486.996 us; speedup vs baseline: 1.4112x; 1.4112x over previous
//
#include <hip/hip_runtime.h>
#include <cfloat>

#define NTOK 65536
#define DIM  512
#define KCB  1024
#define TAU  0.05f
#define REF_CAP 4096

typedef unsigned short u16;
typedef __attribute__((ext_vector_type(8))) short short8;
typedef __attribute__((ext_vector_type(4))) float f32x4;

// ---------------- ws layout (bytes) ----------------
// 0       : idx       int[NTOK]        262144
// 262144  : esq       f32[KCB]         4096    -> 266240
// 266240  : refCount  int (16B pad)            -> 266256
// 266256  : refList   int[REF_CAP]     16384   -> 282640
// 282640  : n         f32                      -> 282656 (pad)
// 282656  : counts    int[KCB]         4096    -> 286752
// 286752  : cursor    int[KCB]         4096    -> 290848
// 290848  : base      int[KCB]         4096    -> 294944
// 294976  : E_hi      u16[KCB*DIM]     1048576 -> 1343552
// 1343552 : E_lo      u16[KCB*DIM]     1048576 -> 2392128
// esum f32[KCB*DIM] (2 MB) aliases Ehi+Elo (dead after score_kernel)
// toklist int[NTOK] lives in d_out's out2 region (dead until out24_kernel)

__device__ __forceinline__ u16 f2bf(float f) {
    unsigned int u = __float_as_uint(f);
    u += 0x7FFF + ((u >> 16) & 1);
    return (u16)(u >> 16);
}
__device__ __forceinline__ float bf2f(u16 h) {
    return __uint_as_float(((unsigned int)h) << 16);
}

__global__ __launch_bounds__(256) void esq_kernel(const float* __restrict__ E,
                                                  float* __restrict__ esq)
{
    const int lane = threadIdx.x & 63;
    const int wv   = threadIdx.x >> 6;
    const int k    = blockIdx.x * 4 + wv;
    const float* er = E + (size_t)k * DIM + lane * 8;
    float4 a = *(const float4*)er;
    float4 b = *(const float4*)(er + 4);
    float s = a.x*a.x + a.y*a.y + a.z*a.z + a.w*a.w
            + b.x*b.x + b.y*b.y + b.z*b.z + b.w*b.w;
    for (int off = 32; off > 0; off >>= 1) s += __shfl_down(s, off, 64);
    if (lane == 0) esq[k] = s;
}

// Decompose E into bf16 hi + bf16 residual lo (row-major [KCB][DIM])
__global__ __launch_bounds__(256) void ehilo_kernel(const float* __restrict__ E,
                                                    u16* __restrict__ Ehi,
                                                    u16* __restrict__ Elo)
{
    const size_t i = (size_t)blockIdx.x * 256 + threadIdx.x;   // pair index
    const float2 v = *(const float2*)(E + i * 2);
    const u16 h0 = f2bf(v.x), h1 = f2bf(v.y);
    const u16 l0 = f2bf(v.x - bf2f(h0)), l1 = f2bf(v.y - bf2f(h1));
    ((unsigned int*)Ehi)[i] = ((unsigned int)h1 << 16) | h0;
    ((unsigned int*)Elo)[i] = ((unsigned int)l1 << 16) | l0;
}

// MFMA split-bf16 scoring: 64 tokens/block (16/wave, K=512 in regs),
// 64 chunks of 16 codes staged in swizzled LDS.
__global__ __launch_bounds__(256, 2) void score_kernel(
    const float* __restrict__ z,
    const u16* __restrict__ Ehi, const u16* __restrict__ Elo,
    const float* __restrict__ esq,
    int* __restrict__ idx_ws, float* __restrict__ idx_out,
    int* __restrict__ refCount, int* __restrict__ refList)
{
    __shared__ u16 ehi_t[16 * 512];     // 16 KB, slot-swizzled rows
    __shared__ u16 elo_t[16 * 512];     // 16 KB
    __shared__ float esq_lds[KCB];      // 4 KB

    const int tid  = threadIdx.x;
    const int lane = tid & 63;
    const int wv   = tid >> 6;
    const int blk  = blockIdx.x;
    const int tokbase = blk * 64 + wv * 16;

    for (int i = tid; i < KCB; i += 256) esq_lds[i] = esq[i];

    // A fragments: 16 tokens x K=512, bf16 hi/lo, in registers
    short8 zh[16], zl[16];
    {
        const float* zr = z + (size_t)(tokbase + (lane & 15)) * DIM + ((lane >> 4) << 3);
        #pragma unroll
        for (int kc = 0; kc < 16; ++kc) {
            float4 a = *(const float4*)(zr + kc * 32);
            float4 b = *(const float4*)(zr + kc * 32 + 4);
            float v[8] = {a.x, a.y, a.z, a.w, b.x, b.y, b.z, b.w};
            short8 h, l;
            #pragma unroll
            for (int j = 0; j < 8; ++j) {
                const u16 hb = f2bf(v[j]);
                h[j] = (short)hb;
                l[j] = (short)f2bf(v[j] - bf2f(hb));
            }
            zh[kc] = h; zl[kc] = l;
        }
    }

    float d1[4], d2[4]; int i1[4];
    #pragma unroll
    for (int r = 0; r < 4; ++r) { d1[r] = FLT_MAX; d2[r] = FLT_MAX; i1[r] = KCB; }

    for (int ch = 0; ch < 64; ++ch) {
        __syncthreads();
        #pragma unroll
        for (int i = 0; i < 4; ++i) {
            const int c = (wv << 2) + i;
            const size_t grow = (size_t)((ch << 4) + c) * 512;
            const int soff = (lane ^ (c & 7)) << 3;
            __builtin_amdgcn_global_load_lds(
                (const __attribute__((address_space(1))) void*)(Ehi + grow + soff),
                (__attribute__((address_space(3))) void*)&ehi_t[c * 512], 16, 0, 0);
            __builtin_amdgcn_global_load_lds(
                (const __attribute__((address_space(1))) void*)(Elo + grow + soff),
                (__attribute__((address_space(3))) void*)&elo_t[c * 512], 16, 0, 0);
        }
        __syncthreads();

        f32x4 acc = {0.f, 0.f, 0.f, 0.f};
        #pragma unroll
        for (int kc = 0; kc < 16; ++kc) {
            const int slot = (kc << 2) + (lane >> 4);
            const int base = (lane & 15) * 512 + ((slot ^ (lane & 7)) << 3);
            const short8 eh = *(const short8*)&ehi_t[base];
            const short8 el = *(const short8*)&elo_t[base];
            acc = __builtin_amdgcn_mfma_f32_16x16x32_bf16(zh[kc], eh, acc, 0, 0, 0);
            acc = __builtin_amdgcn_mfma_f32_16x16x32_bf16(zh[kc], el, acc, 0, 0, 0);
            acc = __builtin_amdgcn_mfma_f32_16x16x32_bf16(zl[kc], eh, acc, 0, 0, 0);
        }

        const int code = (ch << 4) + (lane & 15);
        const float ej = esq_lds[code];
        #pragma unroll
        for (int r = 0; r < 4; ++r) {
            const float dist = fmaf(-2.0f, acc[r], ej);
            if (dist < d1[r]) { d2[r] = d1[r]; d1[r] = dist; i1[r] = code; }
            else              { d2[r] = fminf(d2[r], dist); }
        }
    }

    #pragma unroll
    for (int off = 1; off < 16; off <<= 1) {
        #pragma unroll
        for (int r = 0; r < 4; ++r) {
            const float od1 = __shfl_xor(d1[r], off, 64);
            const int   oi1 = __shfl_xor(i1[r], off, 64);
            const float od2 = __shfl_xor(d2[r], off, 64);
            float loser;
            if (od1 < d1[r] || (od1 == d1[r] && oi1 < i1[r])) {
                loser = d1[r]; d1[r] = od1; i1[r] = oi1;
            } else {
                loser = od1;
            }
            d2[r] = fminf(fminf(d2[r], od2), loser);
        }
    }
    if ((lane & 15) == 0) {
        #pragma unroll
        for (int r = 0; r < 4; ++r) {
            const int token = tokbase + ((lane >> 4) << 2) + r;
            idx_ws[token]  = i1[r];
            idx_out[token] = (float)i1[r];
            if (d2[r] - d1[r] < TAU) {
                int slot = atomicAdd(refCount, 1);
                if (slot < REF_CAP) refList[slot] = token;
            }
        }
    }
}

// f64 exact re-scoring of near-tie tokens against all 1024 codes
__global__ __launch_bounds__(256) void refine_kernel(
    const float* __restrict__ z, const float* __restrict__ E,
    const int* __restrict__ refCount, const int* __restrict__ refList,
    int* __restrict__ idx_ws, float* __restrict__ idx_out)
{
    __shared__ double dists[KCB];
    const int lane = threadIdx.x & 63;
    const int wv   = threadIdx.x >> 6;
    int rc = *refCount; if (rc > REF_CAP) rc = REF_CAP;
    for (int r = blockIdx.x; r < rc; r += gridDim.x) {
        const int token = refList[r];
        double zr[8];
        const float* zp = z + (size_t)token * DIM + lane * 8;
        #pragma unroll
        for (int j = 0; j < 8; ++j) zr[j] = (double)zp[j];
        for (int c = wv; c < KCB; c += 4) {
            const float* ep = E + (size_t)c * DIM + lane * 8;
            double s = 0.0;
            #pragma unroll
            for (int j = 0; j < 8; ++j) { const double df = zr[j] - (double)ep[j]; s = fma(df, df, s); }
            for (int off = 32; off > 0; off >>= 1) s += __shfl_down(s, off, 64);
            if (lane == 0) dists[c] = s;
        }
        __syncthreads();
        if (threadIdx.x < 64) {
            double best = dists[lane]; int bi = lane;
            for (int c = lane + 64; c < KCB; c += 64) {
                const double dv = dists[c];
                if (dv < best) { best = dv; bi = c; }
            }
            for (int off = 32; off > 0; off >>= 1) {
                const double ob = __shfl_down(best, off, 64);
                const int    oi = __shfl_down(bi, off, 64);
                if (ob < best || (ob == best && oi < bi)) { best = ob; bi = oi; }
            }
            if (lane == 0) { idx_ws[token] = bi; idx_out[token] = (float)bi; }
        }
        __syncthreads();
    }
}

// ---- counting sort of tokens by code ----
__global__ __launch_bounds__(256) void hist_kernel(const int* __restrict__ idx,
                                                   int* __restrict__ counts)
{
    __shared__ int h[KCB];
    const int tid = threadIdx.x;
    for (int i = tid; i < KCB; i += 256) h[i] = 0;
    __syncthreads();
    const int b0 = blockIdx.x * 1024;
    #pragma unroll
    for (int j = 0; j < 4; ++j) atomicAdd(&h[idx[b0 + j * 256 + tid]], 1);
    __syncthreads();
    for (int i = tid; i < KCB; i += 256) {
        const int v = h[i];
        if (v) atomicAdd(&counts[i], v);
    }
}

__global__ __launch_bounds__(1024) void scan_kernel(const int* __restrict__ counts,
                                                    int* __restrict__ cursor,
                                                    int* __restrict__ base)
{
    const int tid = threadIdx.x, lane = tid & 63, wv = tid >> 6;
    const int v = counts[tid];
    int s = v;
    #pragma unroll
    for (int off = 1; off < 64; off <<= 1) {
        const int nb = __shfl_up(s, off, 64);
        if (lane >= off) s += nb;
    }
    __shared__ int wsum[16], wbase[16];
    if (lane == 63) wsum[wv] = s;
    __syncthreads();
    if (tid == 0) {
        int r = 0;
        for (int w = 0; w < 16; ++w) { wbase[w] = r; r += wsum[w]; }
    }
    __syncthreads();
    const int excl = wbase[wv] + s - v;
    cursor[tid] = excl;
    base[tid]   = excl;
}

__global__ __launch_bounds__(256) void scatter_kernel(const int* __restrict__ idx,
                                                      int* __restrict__ cursor,
                                                      int* __restrict__ toklist)
{
    const int b0 = blockIdx.x * 1024;
    #pragma unroll
    for (int j = 0; j < 4; ++j) {
        const int t = b0 + j * 256 + threadIdx.x;
        const int k = idx[t];
        const int slot = atomicAdd(&cursor[k], 1);
        toklist[slot] = t;
    }
}

// Uniform-work segment sum: block b owns sorted slots [b*64, b*64+64).
// Tokens sorted by code -> few runs/segment; per run accumulate z rows in
// regs, flush ONE atomic row-add to esum[k]. Fused out0[t] = E[k] write.
__global__ __launch_bounds__(256) void seg_sum_kernel(
    const float* __restrict__ z, const float* __restrict__ E,
    const int* __restrict__ toklist, const int* __restrict__ idx,
    float* __restrict__ out0, float* __restrict__ esum)
{
    __shared__ int toks[64];
    __shared__ int ks[64];
    const int tid  = threadIdx.x;
    const int seg0 = blockIdx.x * 64;
    if (tid < 64) toks[tid] = toklist[seg0 + tid];
    __syncthreads();
    if (tid < 64) ks[tid] = idx[toks[tid]];
    __syncthreads();

    const int d = tid * 2;
    int curk = ks[0];
    float2 er  = *(const float2*)(E + (size_t)curk * DIM + d);
    float2 acc = {0.f, 0.f};
    float2 v   = *(const float2*)(z + (size_t)toks[0] * DIM + d);
    for (int i = 0; i < 64; ++i) {
        const int t = toks[i];
        float2 vn;
        if (i < 63) vn = *(const float2*)(z + (size_t)toks[i + 1] * DIM + d);
        const int k = ks[i];
        if (k != curk) {                       // block-uniform branch (~2/segment)
            atomicAdd(&esum[(size_t)curk * DIM + d],     acc.x);
            atomicAdd(&esum[(size_t)curk * DIM + d + 1], acc.y);
            acc.x = 0.f; acc.y = 0.f;
            curk = k;
            er = *(const float2*)(E + (size_t)k * DIM + d);
        }
        *(float2*)(out0 + (size_t)t * DIM + d) = er;
        acc.x += v.x; acc.y += v.y;
        v = vn;
    }
    atomicAdd(&esum[(size_t)curk * DIM + d],     acc.x);
    atomicAdd(&esum[(size_t)curk * DIM + d + 1], acc.y);
}

__global__ __launch_bounds__(1024) void cs_n_kernel(const float* __restrict__ cs,
    const int* __restrict__ counts, float* __restrict__ out3,
    float* __restrict__ n_ws)
{
    const int k = threadIdx.x;
    const float ncs = 0.99f * cs[k] + 0.01f * (float)counts[k];
    out3[k] = ncs;
    float s = ncs;
    for (int off = 32; off > 0; off >>= 1) s += __shfl_down(s, off, 64);
    __shared__ float red[16];
    const int lane = k & 63, wv = k >> 6;
    if (lane == 0) red[wv] = s;
    __syncthreads();
    if (k == 0) {
        float t = 0.f;
        for (int i = 0; i < 16; ++i) t += red[i];
        n_ws[0] = t;
    }
}

__global__ __launch_bounds__(256) void out24_kernel(const float* __restrict__ ea,
    const float* __restrict__ esum, const float* __restrict__ out3,
    const float* __restrict__ n_ws, float* __restrict__ out2,
    float* __restrict__ out4)
{
    const size_t i = (size_t)blockIdx.x * 256 + threadIdx.x;
    const int k = (int)(i >> 9);
    const float n = n_ws[0];
    const float smoothed = (out3[k] + 1e-5f) / (n + 0.01024f) * n;
    const float nea = 0.99f * ea[i] + 0.01f * esum[i];
    out4[i] = nea;
    out2[i] = nea / smoothed;
}

extern "C" void kernel_launch(void* const* d_in, const int* in_sizes, int n_in,
                              void* d_out, int out_size, void* d_ws, size_t ws_size,
                              hipStream_t stream)
{
    const float* z  = (const float*)d_in[0];
    const float* E  = (const float*)d_in[1];
    const float* cs = (const float*)d_in[2];
    const float* ea = (const float*)d_in[3];

    float* out0 = (float*)d_out;                       // quantized_st [NTOK*DIM]
    float* out1 = out0 + (size_t)NTOK * DIM;           // indices (as f32) [NTOK]
    float* out2 = out1 + NTOK;                         // new_embedding [KCB*DIM]
    float* out3 = out2 + (size_t)KCB * DIM;            // new_cluster_size [KCB]
    float* out4 = out3 + KCB;                          // new_embed_avg [KCB*DIM]

    char* ws = (char*)d_ws;
    int*   idx_ws  = (int*)ws;
    float* esq     = (float*)(ws + 262144);
    int*   refCnt  = (int*)(ws + 266240);
    int*   refList = (int*)(ws + 266256);
    float* n_ws    = (float*)(ws + 282640);
    int*   counts  = (int*)(ws + 282656);
    int*   cursor  = (int*)(ws + 286752);
    int*   base    = (int*)(ws + 290848);
    u16*   Ehi     = (u16*)(ws + 294976);
    u16*   Elo     = (u16*)(ws + 1343552);
    float* esum    = (float*)(ws + 294976);            // aliases Ehi+Elo (2 MB)
    int*   toklist = (int*)out2;                       // out2 region as scratch

    hipMemsetAsync(refCnt, 0, sizeof(int), stream);
    hipMemsetAsync(counts, 0, KCB * sizeof(int), stream);

    esq_kernel<<<KCB / 4, 256, 0, stream>>>(E, esq);
    ehilo_kernel<<<(KCB * DIM / 2) / 256, 256, 0, stream>>>(E, Ehi, Elo);
    score_kernel<<<NTOK / 64, 256, 0, stream>>>(z, Ehi, Elo, esq, idx_ws, out1, refCnt, refList);
    // Ehi/Elo dead from here; zero esum over that region (stream-ordered)
    hipMemsetAsync(esum, 0, (size_t)KCB * DIM * sizeof(float), stream);
    refine_kernel<<<256, 256, 0, stream>>>(z, E, refCnt, refList, idx_ws, out1);
    hist_kernel<<<NTOK / 1024, 256, 0, stream>>>(idx_ws, counts);
    scan_kernel<<<1, 1024, 0, stream>>>(counts, cursor, base);
    scatter_kernel<<<NTOK / 1024, 256, 0, stream>>>(idx_ws, cursor, toklist);
    seg_sum_kernel<<<NTOK / 64, 256, 0, stream>>>(z, E, toklist, idx_ws, out0, esum);
    cs_n_kernel<<<1, 1024, 0, stream>>>(cs, counts, out3, n_ws);
    out24_kernel<<<(KCB * DIM) / 256, 256, 0, stream>>>(ea, esum, out3, n_ws, out2, out4);
}